// Round 4
// baseline (268.090 us; speedup 1.0000x reference)
//
#include <hip/hip_runtime.h>
#include <math.h>

#define LL 512
#define EE 1024
#define HH 16
#define DD 64
#define NSX 16               // N*S
#define NT (NSX*LL)          // 8192 tokens
#define NSLE (NT*EE)         // 8388608
// q is pre-scaled by (1/sqrt(512)) * log2(e) so softmax uses native exp2
#define SCALE_Q 0.06375871f

typedef unsigned short u16;
typedef short bf16x8 __attribute__((ext_vector_type(8)));
typedef float f32x4 __attribute__((ext_vector_type(4)));

__device__ inline u16 f2bf(float f) {
  unsigned u = __float_as_uint(f);
  u += 0x7fff + ((u >> 16) & 1);          // RNE
  return (u16)(u >> 16);
}

// direct builtin calls only; ONLY gfx950-verified MFMA shapes (16x16x32)
#define FEXP2(x) __builtin_amdgcn_exp2f(x)
#define MFMA32(a, b, c) __builtin_amdgcn_mfma_f32_16x16x32_bf16((a), (b), (c), 0, 0, 0)

// async 16B global->LDS (wave-uniform LDS base + lane*16 layout)
__device__ inline void gload16(const void* g, void* l) {
  __builtin_amdgcn_global_load_lds(
      (const __attribute__((address_space(1))) unsigned int*)g,
      (__attribute__((address_space(3))) unsigned int*)l, 16, 0, 0);
}

// ---------------- K0: convert weights fp32 -> bf16; zero csum ----------------
__global__ void __launch_bounds__(256) convw_kernel(
    const float* __restrict__ Wv, const float* __restrict__ Wk,
    const float* __restrict__ Wq, const float* __restrict__ Wo,
    u16* __restrict__ Wvb, u16* __restrict__ Wkb,
    u16* __restrict__ Wqb, u16* __restrict__ Wob,
    float* __restrict__ csum) {
  int i = blockIdx.x * 256 + threadIdx.x;   // quad index
  const float* s; u16* d; int j;
  if (i < 262144) { s = Wo; d = Wob; j = i; }
  else {
    j = i - 262144;
    if (j < 1024)      { s = Wv; d = Wvb; }
    else if (j < 2048) { s = Wk; d = Wkb; j -= 1024; }
    else if (j < 3072) { s = Wq; d = Wqb; j -= 2048; }
    else {                                   // zero csum (re-zeroed every launch)
      float4 zz = {0.f, 0.f, 0.f, 0.f};
      ((float4*)csum)[j - 3072] = zz;        // 32768 quads = 131072 floats
      return;
    }
  }
  float4 f = ((const float4*)s)[j];
  ushort4 o; o.x = f2bf(f.x); o.y = f2bf(f.y); o.z = f2bf(f.z); o.w = f2bf(f.w);
  ((ushort4*)d)[j] = o;
}

// ---------------- K1: projections via MFMA, LDS-free, 2-deep pipelined ------
// grid = mat(3) x ns(16) x hg(4) x tt0(8) = 1536 blocks; wave = one head; each
// wave processes 4 token-tiles (tt = tt0 + 8j) with loads for tiles j+1 AND
// j+2 in flight while computing tile j.
// v stored transposed vpT[ns][h][d][l] via MFMA(af,wf); k/q stored row-major
// via SWAPPED MFMA(wf,af) (verified r1/r2) so the epilogue is 4 ushort4 stores.
__global__ void __launch_bounds__(256) proj_kernel(
    const float* __restrict__ vals, const float* __restrict__ keys,
    const float* __restrict__ qry,
    const u16* __restrict__ Wvb, const u16* __restrict__ Wkb,
    const u16* __restrict__ Wqb,
    u16* __restrict__ vpT, u16* __restrict__ kp, u16* __restrict__ qp) {
  const int b = blockIdx.x;
  const int tt0 = b & 7, hg = (b >> 3) & 3, ns = (b >> 5) & 15, mat = b >> 9;
  const int tid = threadIdx.x;
  const int wid = tid >> 6, lane = tid & 63, quad = lane >> 4, l16 = lane & 15;
  const int h = hg*4 + wid;
  const float* src = (mat == 0 ? vals : mat == 1 ? keys : qry);
  const u16*   W   = (mat == 0 ? Wvb  : mat == 1 ? Wkb  : Wqb);
  u16* dst = (mat == 1 ? kp : qp);
  const float sc = (mat == 2) ? SCALE_Q : 1.f;
  // ---- W fragments: loaded once, register-resident across all 4 tiles ----
  bf16x8 wf[4][2];
  #pragma unroll
  for (int nt = 0; nt < 4; ++nt) {
    wf[nt][0] = *(const bf16x8*)&W[(nt*16 + l16)*DD + quad*8];
    wf[nt][1] = *(const bf16x8*)&W[(nt*16 + l16)*DD + 32 + quad*8];
  }
  f32x4 z = {0.f, 0.f, 0.f, 0.f};
  // ---- prologue: loads for tiles j=0 and j=1 ----
  const float* xr0 = src + (size_t)(ns*LL + tt0*16 + l16)*EE + h*DD;
  const float* xr1 = xr0 + (size_t)128*EE;             // +8 token-tiles
  float4 x0 = *(const float4*)&xr0[quad*8];
  float4 x1 = *(const float4*)&xr0[quad*8 + 4];
  float4 x2 = *(const float4*)&xr0[32 + quad*8];
  float4 x3 = *(const float4*)&xr0[32 + quad*8 + 4];
  float4 y0 = *(const float4*)&xr1[quad*8];
  float4 y1 = *(const float4*)&xr1[quad*8 + 4];
  float4 y2 = *(const float4*)&xr1[32 + quad*8];
  float4 y3 = *(const float4*)&xr1[32 + quad*8 + 4];
  #pragma unroll
  for (int j = 0; j < 4; ++j) {
    const int tt = tt0 + 8*j;
    const int t0 = ns*LL + tt*16;
    // ---- issue loads for tile j+2 before touching this tile's data ----
    float4 n0, n1, n2, n3;
    if (j < 2) {
      const float* xrn = src + (size_t)(t0 + 256 + l16)*EE + h*DD;  // +16 tiles
      n0 = *(const float4*)&xrn[quad*8];
      n1 = *(const float4*)&xrn[quad*8 + 4];
      n2 = *(const float4*)&xrn[32 + quad*8];
      n3 = *(const float4*)&xrn[32 + quad*8 + 4];
    }
    // ---- convert current tile ----
    bf16x8 af0, af1;
    af0[0] = (short)f2bf(x0.x); af0[1] = (short)f2bf(x0.y);
    af0[2] = (short)f2bf(x0.z); af0[3] = (short)f2bf(x0.w);
    af0[4] = (short)f2bf(x1.x); af0[5] = (short)f2bf(x1.y);
    af0[6] = (short)f2bf(x1.z); af0[7] = (short)f2bf(x1.w);
    af1[0] = (short)f2bf(x2.x); af1[1] = (short)f2bf(x2.y);
    af1[2] = (short)f2bf(x2.z); af1[3] = (short)f2bf(x2.w);
    af1[4] = (short)f2bf(x3.x); af1[5] = (short)f2bf(x3.y);
    af1[6] = (short)f2bf(x3.z); af1[7] = (short)f2bf(x3.w);
    if (mat == 0) {
      // acc[nt][r] = out[token = t0+quad*4+r][d = nt*16+l16]
      f32x4 acc[4];
      #pragma unroll
      for (int nt = 0; nt < 4; ++nt) {
        acc[nt] = MFMA32(af0, wf[nt][0], z);
        acc[nt] = MFMA32(af1, wf[nt][1], acc[nt]);
      }
      // transposed store: rows d = nt*16+l16, 4 consecutive tokens as ushort4
      #pragma unroll
      for (int nt = 0; nt < 4; ++nt) {
        ushort4 o;
        o.x = f2bf(acc[nt][0]); o.y = f2bf(acc[nt][1]);
        o.z = f2bf(acc[nt][2]); o.w = f2bf(acc[nt][3]);
        size_t idx = ((size_t)((ns*HH + h)*DD + nt*16 + l16))*LL + tt*16 + quad*4;
        *(ushort4*)&vpT[idx] = o;
      }
    } else {
      // swapped: acc[nt][r] = out[token = t0+l16][d = nt*16+quad*4+r]
      f32x4 acc[4];
      #pragma unroll
      for (int nt = 0; nt < 4; ++nt) {
        acc[nt] = MFMA32(wf[nt][0], af0, z);
        acc[nt] = MFMA32(wf[nt][1], af1, acc[nt]);
      }
      #pragma unroll
      for (int nt = 0; nt < 4; ++nt) {
        ushort4 o;
        o.x = f2bf(acc[nt][0] * sc); o.y = f2bf(acc[nt][1] * sc);
        o.z = f2bf(acc[nt][2] * sc); o.w = f2bf(acc[nt][3] * sc);
        *(ushort4*)&dst[(size_t)(t0 + l16)*EE + h*DD + nt*16 + quad*4] = o;
      }
    }
    x0 = y0; x1 = y1; x2 = y2; x3 = y3;
    if (j < 2) { y0 = n0; y1 = n1; y2 = n2; y3 = n3; }
  }
}

// ---------------- K2a: column-softmax denominators (atomic) ----------------
// csum[ns][h][l] = sum_q mask_q * exp2(e_ql). LDS-FREE, fully streaming:
// kf read from global (L2/L3-hot, 16 MB), per-wave partials via shfl, one
// masked atomicAdd per 16-l group. grid = ns(16) x h(16) x qs(4) x ls(2)
// = 2048 blocks x 4 waves -> high occupancy, no barriers.
__global__ void __launch_bounds__(256) attn_cs_kernel(
    const u16* __restrict__ qp, const u16* __restrict__ kp,
    const int* __restrict__ mask, float* __restrict__ csum) {
  const int b = blockIdx.x;
  const int ls = b & 1, qs = (b >> 1) & 3, h = (b >> 3) & 15, ns = b >> 7;
  const int tid = threadIdx.x;
  const int wid = tid >> 6, lane = tid & 63, quad = lane >> 4, l16 = lane & 15;
  const int q0 = qs*128 + wid*32;
  bf16x8 qf[2][2];
  float maf[2][4];
  #pragma unroll
  for (int qt = 0; qt < 2; ++qt) {
    const u16* qrow = qp + ((size_t)(ns*LL + q0 + qt*16 + l16))*EE + h*DD;
    qf[qt][0] = *(const bf16x8*)&qrow[quad*8];
    qf[qt][1] = *(const bf16x8*)&qrow[32 + quad*8];
    #pragma unroll
    for (int r = 0; r < 4; ++r)
      maf[qt][r] = mask[ns*LL + q0 + qt*16 + quad*4 + r] ? 1.f : 0.f;
  }
  f32x4 z = {0.f, 0.f, 0.f, 0.f};
  const u16* kbase = kp + ((size_t)(ns*LL + ls*256))*EE + h*DD;
  float* cbase = csum + (ns*HH + h)*LL + ls*256;
  #pragma unroll 4
  for (int lt = 0; lt < 16; ++lt) {
    const u16* krow = kbase + (size_t)(lt*16 + l16)*EE;
    bf16x8 kf0 = *(const bf16x8*)&krow[quad*8];
    bf16x8 kf1 = *(const bf16x8*)&krow[32 + quad*8];
    float part = 0.f;
    #pragma unroll
    for (int qt = 0; qt < 2; ++qt) {
      f32x4 e = MFMA32(qf[qt][0], kf0, z);
      e = MFMA32(qf[qt][1], kf1, e);
      #pragma unroll
      for (int r = 0; r < 4; ++r)
        part += maf[qt][r] * FEXP2(e[r]);     // e row = q(quad*4+r), col = l(l16)
    }
    part += __shfl_xor(part, 16);             // combine 4 quads (same l16)
    part += __shfl_xor(part, 32);
    if (quad == 0) atomicAdd(&cbase[lt*16 + l16], part);
  }
}

// ---------------- K2b: attention-out (PV) ----------------
// grid = ns(16) x h(16) x qs(4) = 1024 blocks x 4 waves. kf from GLOBAL
// (no Ks LDS), csinv in 2KB LDS, V chunk double-buffered (18KB), per-wave
// pt (10KB) => 31KB LDS -> ~4 independent blocks/CU overlapping stalls.
// Body = verified r3 phase-B (E^T = MFMA(K,Q) -> ushort4 P -> pa/vb MFMA),
// with vb hoisted out of the qt loop (halves vb b128 reads).
__global__ void __launch_bounds__(256) attn_pv_kernel(
    const u16* __restrict__ qp, const u16* __restrict__ kp,
    const u16* __restrict__ vpT, const int* __restrict__ mask,
    const float* __restrict__ csum, u16* __restrict__ oat) {
  const int b = blockIdx.x;
  const int qs = b & 3, h = (b >> 2) & 15, ns = b >> 6;
  const int tid = threadIdx.x;
  const int wid = tid >> 6, lane = tid & 63, quad = lane >> 4, l16 = lane & 15;
  __shared__ u16 Vt[2][DD][72];     // V^T[d][l64] dbuf  18432 B
  __shared__ u16 pt[4][32][40];     // per-wave P        10240 B
  __shared__ float csinv[LL];       //                    2048 B => 30720 B
  // ---- load csinv ----
  const float* cbase = csum + (ns*HH + h)*LL;
  for (int i = tid; i < LL; i += 256) {
    float s = cbase[i];
    csinv[i] = (s > 0.f) ? 1.f/s : 0.f;
  }
  // ---- persistent Q fragments (wave owns 32 q rows) + mask ----
  const int q0 = qs*128 + wid*32;
  bf16x8 qf[2][2];
  float mqf[2];       // q = q0+qt*16+l16 (E^T orientation)
  #pragma unroll
  for (int qt = 0; qt < 2; ++qt) {
    const u16* qrow = qp + ((size_t)(ns*LL + q0 + qt*16 + l16))*EE + h*DD;
    qf[qt][0] = *(const bf16x8*)&qrow[quad*8];
    qf[qt][1] = *(const bf16x8*)&qrow[32 + quad*8];
    mqf[qt] = mask[ns*LL + q0 + qt*16 + l16] ? 1.f : 0.f;
  }
  f32x4 z = {0.f, 0.f, 0.f, 0.f};
  f32x4 acc[4][2] = {{z,z},{z,z},{z,z},{z,z}};   // [dtile][qt]
  const size_t vgbase = ((size_t)((ns*HH + h)*DD))*LL;
  const u16* kbase = kp + ((size_t)(ns*LL))*EE + h*DD;
  __syncthreads();
  for (int lc = 0; lc < 8; ++lc) {               // 8 chunks of 64 l
    {                                            // stage V^T[d][lc*64..+63]
      int row = tid >> 2, seg = (tid & 3) * 16;  // 256 thr x 32B
      const u16* vsrc = &vpT[vgbase + (size_t)row*LL + lc*64 + seg];
      *(bf16x8*)&Vt[lc & 1][row][seg]     = *(const bf16x8*)&vsrc[0];
      *(bf16x8*)&Vt[lc & 1][row][seg + 8] = *(const bf16x8*)&vsrc[8];
    }
    __syncthreads();                             // one barrier per chunk (dbuf)
    // E^T (kf from global) + P as ushort4 + PV
    #pragma unroll
    for (int lt2 = 0; lt2 < 4; ++lt2) {
      const int lb = lc*64 + lt2*16;
      const u16* krow = kbase + (size_t)(lb + l16)*EE;
      bf16x8 kf0 = *(const bf16x8*)&krow[quad*8];
      bf16x8 kf1 = *(const bf16x8*)&krow[32 + quad*8];
      float4 cs4 = *(const float4*)&csinv[lb + quad*4];   // l = lb+quad*4+r
      #pragma unroll
      for (int qt = 0; qt < 2; ++qt) {
        // E^T: lane holds e[l = lb+quad*4+r][q = q0+qt*16+l16]
        f32x4 e = MFMA32(kf0, qf[qt][0], z);
        e = MFMA32(kf1, qf[qt][1], e);
        const float m = mqf[qt];
        ushort4 o;
        o.x = f2bf(m * cs4.x * FEXP2(e[0]));
        o.y = f2bf(m * cs4.y * FEXP2(e[1]));
        o.z = f2bf(m * cs4.z * FEXP2(e[2]));
        o.w = f2bf(m * cs4.w * FEXP2(e[3]));
        // P[q][l]: row q = qt*16+l16, cols l-rel = (lt2&1)*16 + quad*4 .. +3
        *(ushort4*)&pt[wid][qt*16 + l16][(lt2 & 1)*16 + quad*4] = o;
      }
      // PV for the 32-l half once both sub-tiles of it are in pt
      if (lt2 & 1) {
        bf16x8 vb[4];                            // hoisted out of qt loop
        #pragma unroll
        for (int dt = 0; dt < 4; ++dt)
          vb[dt] = *(const bf16x8*)&Vt[lc & 1][dt*16 + l16]
                                      [(lt2 >> 1)*32 + quad*8];
        #pragma unroll
        for (int qt = 0; qt < 2; ++qt) {
          bf16x8 pa = *(const bf16x8*)&pt[wid][qt*16 + l16][quad*8];
          #pragma unroll
          for (int dt = 0; dt < 4; ++dt)
            acc[dt][qt] = MFMA32(pa, vb[dt], acc[dt][qt]);
        }
      }
    }
  }
  // ---- write out[q][d]: D row = q(quad*4+r), col = d(l16) ----
  #pragma unroll
  for (int qt = 0; qt < 2; ++qt)
    #pragma unroll
    for (int dt = 0; dt < 4; ++dt)
      #pragma unroll
      for (int r = 0; r < 4; ++r)
        oat[((size_t)(ns*LL + q0 + qt*16 + quad*4 + r))*EE + h*DD + dt*16 + l16] =
            f2bf(acc[dt][qt][r]);
}

// ---------------- K4: Y = oat @ Wo^T + bo, m97-style MFMA GEMM --------------
// 128x64 tile, BK=64 -> grid 1024 = 4 blocks/CU. 4 waves as 2x2 over
// (128m x 64n), each computing 64x32. Staging via global_load_lds width=16.
__global__ void __launch_bounds__(256) out_gemm_kernel(
    const u16* __restrict__ A, const u16* __restrict__ Wob,
    const float* __restrict__ bo, float* __restrict__ Y) {
  __shared__ u16 As[128][64];   // [m][k]  16384 B, linear for global_load_lds
  __shared__ u16 Bs[64][64];    // [n][k]   8192 B
  const int b = blockIdx.x;     // 64 mtiles x 16 ntiles
  const int nb = b & 15, mb = b >> 4;
  const int m0 = mb*128, n0 = nb*64;
  const int tid = threadIdx.x;
  const int wid = tid >> 6, lane = tid & 63, quad = lane >> 4, l16 = lane & 15;
  const int wm = (wid >> 1)*64, wn = (wid & 1)*32;   // wave sub-tile 64x32
  const int r0 = tid >> 3, sseg = (tid & 7) * 8;     // staging row/col (u16)
  u16* adst = &As[0][0] + tid*8;                     // lane-linear 16B chunks
  u16* bdst = &Bs[0][0] + tid*8;
  f32x4 z = {0.f, 0.f, 0.f, 0.f};
  f32x4 acc[4][2];
  #pragma unroll
  for (int i = 0; i < 4; ++i)
    #pragma unroll
    for (int j = 0; j < 2; ++j) acc[i][j] = z;
  for (int k0 = 0; k0 < EE; k0 += 64) {
    __syncthreads();                    // previous tile fully consumed
    #pragma unroll
    for (int it = 0; it < 4; ++it)      // A: 128 rows x 64 k
      gload16(&A[(size_t)(m0 + it*32 + r0)*EE + k0 + sseg], adst + it*2048);
    #pragma unroll
    for (int it = 0; it < 2; ++it)      // B: 64 rows x 64 k
      gload16(&Wob[(size_t)(n0 + it*32 + r0)*EE + k0 + sseg], bdst + it*2048);
    __syncthreads();                    // vmcnt(0) drain -> LDS data ready
    #pragma unroll
    for (int kk = 0; kk < 2; ++kk) {
      bf16x8 af[4], bfr[2];
      #pragma unroll
      for (int i = 0; i < 4; ++i)
        af[i] = *(const bf16x8*)&As[wm + i*16 + l16][kk*32 + quad*8];
      #pragma unroll
      for (int j = 0; j < 2; ++j)
        bfr[j] = *(const bf16x8*)&Bs[wn + j*16 + l16][kk*32 + quad*8];
      #pragma unroll
      for (int i = 0; i < 4; ++i)
        #pragma unroll
        for (int j = 0; j < 2; ++j)
          acc[i][j] = MFMA32(af[i], bfr[j], acc[i][j]);
    }
  }
  #pragma unroll
  for (int i = 0; i < 4; ++i)
    #pragma unroll
    for (int j = 0; j < 2; ++j) {
      int col = n0 + wn + j*16 + l16;
      float bias = bo[col];
      #pragma unroll
      for (int r = 0; r < 4; ++r)
        Y[(size_t)(m0 + wm + i*16 + quad*4 + r)*EE + col] = acc[i][j][r] + bias;
    }
}

extern "C" void kernel_launch(void* const* d_in, const int* in_sizes, int n_in,
                              void* d_out, int out_size, void* d_ws, size_t ws_size,
                              hipStream_t stream) {
  const float* values = (const float*)d_in[0];
  const float* keysp  = (const float*)d_in[1];
  const float* query  = (const float*)d_in[2];
  const int*   mask   = (const int*)d_in[3];
  const float* Wv = (const float*)d_in[4];
  const float* Wk = (const float*)d_in[5];
  const float* Wq = (const float*)d_in[6];
  const float* Wo = (const float*)d_in[7];
  const float* bo = (const float*)d_in[8];
  float* Y = (float*)d_out;

  u16* qp  = (u16*)d_ws;
  u16* kp  = qp + NSLE;
  u16* vpT = kp + NSLE;
  u16* oat = vpT + NSLE;
  u16* Wob = oat + NSLE;
  u16* Wvb = Wob + EE*EE;
  u16* Wkb = Wvb + DD*DD;
  u16* Wqb = Wkb + DD*DD;
  float* csum = (float*)(Wqb + DD*DD);     // NSX*HH*LL = 131072 floats

  convw_kernel<<<1164, 256, 0, stream>>>(Wv, Wk, Wq, Wo, Wvb, Wkb, Wqb, Wob,
                                         csum);
  proj_kernel<<<3*NSX*4*8, 256, 0, stream>>>(values, keysp, query,
                                             Wvb, Wkb, Wqb, vpT, kp, qp);
  attn_cs_kernel<<<NSX*HH*8, 256, 0, stream>>>(qp, kp, mask, csum);
  attn_pv_kernel<<<NSX*HH*4, 256, 0, stream>>>(qp, kp, vpT, mask, csum, oat);
  out_gemm_kernel<<<(NT/128)*(EE/64), 256, 0, stream>>>(oat, Wob, bo, Y);
}

// Round 5
// 232.807 us; speedup vs baseline: 1.1516x; 1.1516x over previous
//
#include <hip/hip_runtime.h>
#include <math.h>

#define LL 512
#define EE 1024
#define HH 16
#define DD 64
#define NSX 16               // N*S
#define NT (NSX*LL)          // 8192 tokens
#define NSLE (NT*EE)         // 8388608
// q is pre-scaled by (1/sqrt(512)) * log2(e) so softmax uses native exp2
#define SCALE_Q 0.06375871f

typedef unsigned short u16;
typedef short bf16x8 __attribute__((ext_vector_type(8)));
typedef float f32x4 __attribute__((ext_vector_type(4)));

__device__ inline u16 f2bf(float f) {
  unsigned u = __float_as_uint(f);
  u += 0x7fff + ((u >> 16) & 1);          // RNE
  return (u16)(u >> 16);
}

// direct builtin calls only; ONLY gfx950-verified MFMA shapes (16x16x32)
#define FEXP2(x) __builtin_amdgcn_exp2f(x)
#define MFMA32(a, b, c) __builtin_amdgcn_mfma_f32_16x16x32_bf16((a), (b), (c), 0, 0, 0)

// async 16B global->LDS (wave-uniform LDS base + lane*16 layout)
__device__ inline void gload16(const void* g, void* l) {
  __builtin_amdgcn_global_load_lds(
      (const __attribute__((address_space(1))) unsigned int*)g,
      (__attribute__((address_space(3))) unsigned int*)l, 16, 0, 0);
}

// ---------------- K0: convert weights fp32 -> bf16 ----------------
__global__ void __launch_bounds__(256) convw_kernel(
    const float* __restrict__ Wv, const float* __restrict__ Wk,
    const float* __restrict__ Wq, const float* __restrict__ Wo,
    u16* __restrict__ Wvb, u16* __restrict__ Wkb,
    u16* __restrict__ Wqb, u16* __restrict__ Wob) {
  int i = blockIdx.x * 256 + threadIdx.x;   // quad index
  const float* s; u16* d; int j;
  if (i < 262144) { s = Wo; d = Wob; j = i; }
  else {
    j = i - 262144;
    if (j < 1024)      { s = Wv; d = Wvb; }
    else if (j < 2048) { s = Wk; d = Wkb; j -= 1024; }
    else               { s = Wq; d = Wqb; j -= 2048; }
  }
  float4 f = ((const float4*)s)[j];
  ushort4 o; o.x = f2bf(f.x); o.y = f2bf(f.y); o.z = f2bf(f.z); o.w = f2bf(f.w);
  ((ushort4*)d)[j] = o;
}

// ---------------- K1: projections via MFMA, LDS-free, 4-DEEP prologue ------
// grid = mat(3) x ns(16) x hg(4) x tt0(8) = 1536 blocks; wave = one head; each
// wave processes 4 token-tiles with ALL 16 x 16B loads issued in the prologue
// (16 in flight/wave = 2x the r3 MLP; Little's-law fix for the 2.1 TB/s cap).
// v stored transposed vpT[ns][h][d][l] via MFMA(af,wf); k/q stored row-major
// via SWAPPED MFMA(wf,af) (verified r1/r2) so the epilogue is 4 ushort4 stores.
__global__ void __launch_bounds__(256) proj_kernel(
    const float* __restrict__ vals, const float* __restrict__ keys,
    const float* __restrict__ qry,
    const u16* __restrict__ Wvb, const u16* __restrict__ Wkb,
    const u16* __restrict__ Wqb,
    u16* __restrict__ vpT, u16* __restrict__ kp, u16* __restrict__ qp) {
  const int b = blockIdx.x;
  const int tt0 = b & 7, hg = (b >> 3) & 3, ns = (b >> 5) & 15, mat = b >> 9;
  const int tid = threadIdx.x;
  const int wid = tid >> 6, lane = tid & 63, quad = lane >> 4, l16 = lane & 15;
  const int h = hg*4 + wid;
  const float* src = (mat == 0 ? vals : mat == 1 ? keys : qry);
  const u16*   W   = (mat == 0 ? Wvb  : mat == 1 ? Wkb  : Wqb);
  u16* dst = (mat == 1 ? kp : qp);
  const float sc = (mat == 2) ? SCALE_Q : 1.f;
  // ---- prologue: issue ALL 4 tiles' X loads first (16 x 16B in flight) ----
  float4 x[4][4];
  #pragma unroll
  for (int j = 0; j < 4; ++j) {
    const float* xr = src + (size_t)(ns*LL + (tt0 + 8*j)*16 + l16)*EE + h*DD;
    x[j][0] = *(const float4*)&xr[quad*8];
    x[j][1] = *(const float4*)&xr[quad*8 + 4];
    x[j][2] = *(const float4*)&xr[32 + quad*8];
    x[j][3] = *(const float4*)&xr[32 + quad*8 + 4];
  }
  // ---- W fragments (L2-hot, issued after the long-pole X loads) ----
  bf16x8 wf[4][2];
  #pragma unroll
  for (int nt = 0; nt < 4; ++nt) {
    wf[nt][0] = *(const bf16x8*)&W[(nt*16 + l16)*DD + quad*8];
    wf[nt][1] = *(const bf16x8*)&W[(nt*16 + l16)*DD + 32 + quad*8];
  }
  f32x4 z = {0.f, 0.f, 0.f, 0.f};
  #pragma unroll
  for (int j = 0; j < 4; ++j) {
    const int tt = tt0 + 8*j;
    const int t0 = ns*LL + tt*16;
    // ---- convert tile j (indices compile-time after unroll) ----
    bf16x8 af0, af1;
    af0[0] = (short)f2bf(x[j][0].x); af0[1] = (short)f2bf(x[j][0].y);
    af0[2] = (short)f2bf(x[j][0].z); af0[3] = (short)f2bf(x[j][0].w);
    af0[4] = (short)f2bf(x[j][1].x); af0[5] = (short)f2bf(x[j][1].y);
    af0[6] = (short)f2bf(x[j][1].z); af0[7] = (short)f2bf(x[j][1].w);
    af1[0] = (short)f2bf(x[j][2].x); af1[1] = (short)f2bf(x[j][2].y);
    af1[2] = (short)f2bf(x[j][2].z); af1[3] = (short)f2bf(x[j][2].w);
    af1[4] = (short)f2bf(x[j][3].x); af1[5] = (short)f2bf(x[j][3].y);
    af1[6] = (short)f2bf(x[j][3].z); af1[7] = (short)f2bf(x[j][3].w);
    if (mat == 0) {
      // acc[nt][r] = out[token = t0+quad*4+r][d = nt*16+l16]
      f32x4 acc[4];
      #pragma unroll
      for (int nt = 0; nt < 4; ++nt) {
        acc[nt] = MFMA32(af0, wf[nt][0], z);
        acc[nt] = MFMA32(af1, wf[nt][1], acc[nt]);
      }
      // transposed store: rows d = nt*16+l16, 4 consecutive tokens as ushort4
      #pragma unroll
      for (int nt = 0; nt < 4; ++nt) {
        ushort4 o;
        o.x = f2bf(acc[nt][0]); o.y = f2bf(acc[nt][1]);
        o.z = f2bf(acc[nt][2]); o.w = f2bf(acc[nt][3]);
        size_t idx = ((size_t)((ns*HH + h)*DD + nt*16 + l16))*LL + tt*16 + quad*4;
        *(ushort4*)&vpT[idx] = o;
      }
    } else {
      // swapped: acc[nt][r] = out[token = t0+l16][d = nt*16+quad*4+r]
      f32x4 acc[4];
      #pragma unroll
      for (int nt = 0; nt < 4; ++nt) {
        acc[nt] = MFMA32(wf[nt][0], af0, z);
        acc[nt] = MFMA32(wf[nt][1], af1, acc[nt]);
      }
      #pragma unroll
      for (int nt = 0; nt < 4; ++nt) {
        ushort4 o;
        o.x = f2bf(acc[nt][0] * sc); o.y = f2bf(acc[nt][1] * sc);
        o.z = f2bf(acc[nt][2] * sc); o.w = f2bf(acc[nt][3] * sc);
        *(ushort4*)&dst[(size_t)(t0 + l16)*EE + h*DD + nt*16 + quad*4] = o;
      }
    }
  }
}

// ---------------- K2: fused column-softmax + attention-out ----------------
// one block per (ns,h): 256 blocks x 1024 threads. K resident in LDS.
// softmax over the QUERY axis: csum_l = sum_q m_q*exp2(e).
// Phase B = r3-verified body (E^T = MFMA(K,Q) -> ushort4 P -> pa/vb MFMA),
// now with TRUE V pipelining (T14): chunk-0 V loads issued at kernel start
// (latency hidden under phase A); per chunk, next-chunk loads issue BEFORE
// compute and the reg->LDS write lands AFTER compute; one barrier per chunk.
// vb hoisted out of the qt loop (halves Vt b128 reads). No setprio (r2: -5%).
__global__ void __launch_bounds__(1024, 4) attn_kernel(
    const u16* __restrict__ qp, const u16* __restrict__ kp,
    const u16* __restrict__ vpT, const int* __restrict__ mask,
    u16* __restrict__ oat) {
  const int b = blockIdx.x;
  const int h = b & 15, ns = b >> 4;
  const int tid = threadIdx.x;
  const int wid = tid >> 6, lane = tid & 63, quad = lane >> 4, l16 = lane & 15;
  __shared__ u16 Ks[LL][72];        // K[l][d]      73728 B
  __shared__ u16 Vt[2][DD][72];     // V^T[d][l64]  18432 B
  __shared__ u16 pt[16][32][40];    // per-wave P   40960 B (phase A: psum f32[16][512])
  __shared__ float csum[LL];        //               2048 B   => 135168 B total
  float* psum = (float*)pt;
  // ---- V chunk-0 prefetch into regs (latency hides under phase A) ----
  const size_t vgbase = ((size_t)((ns*HH + h)*DD))*LL;
  const int vrow = tid >> 4, vseg = (tid & 15) * 4;   // 64 rows x 16 segs of 8B
  ushort4 vreg = *(const ushort4*)&vpT[vgbase + (size_t)vrow*LL + vseg];
  // ---- stage K ----
  const size_t kgbase = ((size_t)(ns*LL))*EE + h*DD;
  for (int i = tid; i < 4096; i += 1024) {          // 512 rows x 8 segs of 16B
    int row = i >> 3, seg = (i & 7) * 8;
    *(bf16x8*)&Ks[row][seg] = *(const bf16x8*)&kp[kgbase + (size_t)row*EE + seg];
  }
  // ---- persistent Q fragments (wave owns 32 q rows) + masks ----
  const int q0 = wid*32;
  bf16x8 qf[2][2];
  float maf[2][4];    // phase A: q = q0+qt*16+quad*4+r
  float mqf[2];       // phase B: q = q0+qt*16+l16 (E^T orientation)
  #pragma unroll
  for (int qt = 0; qt < 2; ++qt) {
    const u16* qrow = qp + ((size_t)(ns*LL + q0 + qt*16 + l16))*EE + h*DD;
    qf[qt][0] = *(const bf16x8*)&qrow[quad*8];
    qf[qt][1] = *(const bf16x8*)&qrow[32 + quad*8];
    #pragma unroll
    for (int r = 0; r < 4; ++r)
      maf[qt][r] = mask[ns*LL + q0 + qt*16 + quad*4 + r] ? 1.f : 0.f;
    mqf[qt] = mask[ns*LL + q0 + qt*16 + l16] ? 1.f : 0.f;
  }
  f32x4 z = {0.f, 0.f, 0.f, 0.f};
  __syncthreads();
  // ---- phase A: column partial sums -> psum[wid][l], then block reduce ----
  for (int lt = 0; lt < 32; ++lt) {
    bf16x8 kf0 = *(const bf16x8*)&Ks[lt*16 + l16][quad*8];
    bf16x8 kf1 = *(const bf16x8*)&Ks[lt*16 + l16][32 + quad*8];
    float part = 0.f;
    #pragma unroll
    for (int qt = 0; qt < 2; ++qt) {
      f32x4 e = MFMA32(qf[qt][0], kf0, z);
      e = MFMA32(qf[qt][1], kf1, e);
      #pragma unroll
      for (int r = 0; r < 4; ++r)
        part += maf[qt][r] * FEXP2(e[r]);     // e row = q(quad*4+r), col = l(l16)
    }
    part += __shfl_xor(part, 16);             // combine 4 quads (same l16)
    part += __shfl_xor(part, 32);
    if (quad == 0) psum[wid*512 + lt*16 + l16] = part;
  }
  __syncthreads();
  if (tid < LL) {
    float s = 0.f;
    #pragma unroll
    for (int w = 0; w < 16; ++w) s += psum[w*512 + tid];
    csum[tid] = (s > 0.f) ? 1.f/s : 0.f;
  }
  __syncthreads();
  // ---- write prefetched chunk 0 into Vt[0] ----
  *(ushort4*)&Vt[0][vrow][vseg] = vreg;
  // ---- phase B: E^T recompute -> P via ushort4 -> PV, V chunks of 64 l ----
  f32x4 acc[4][2] = {{z,z},{z,z},{z,z},{z,z}};   // [dtile][qt]
  for (int lc = 0; lc < 8; ++lc) {               // 8 chunks of 64 l
    // issue NEXT chunk's V loads (regs) before compute — latency hides under it
    ushort4 nreg;
    if (lc < 7)
      nreg = *(const ushort4*)&vpT[vgbase + (size_t)vrow*LL + (lc+1)*64 + vseg];
    __syncthreads();                             // Vt[lc&1] writes now visible
    // E^T + P for 64 l in 4 sub-tiles of 16
    #pragma unroll
    for (int lt2 = 0; lt2 < 4; ++lt2) {
      const int lb = lc*64 + lt2*16;
      bf16x8 kf0 = *(const bf16x8*)&Ks[lb + l16][quad*8];
      bf16x8 kf1 = *(const bf16x8*)&Ks[lb + l16][32 + quad*8];
      float4 cs4 = *(const float4*)&csum[lb + quad*4];   // csum for l=lb+quad*4+r
      #pragma unroll
      for (int qt = 0; qt < 2; ++qt) {
        // E^T: lane holds e[l = lb+quad*4+r][q = q0+qt*16+l16]
        f32x4 e = MFMA32(kf0, qf[qt][0], z);
        e = MFMA32(kf1, qf[qt][1], e);
        const float m = mqf[qt];
        ushort4 o;
        o.x = f2bf(m * cs4.x * FEXP2(e[0]));
        o.y = f2bf(m * cs4.y * FEXP2(e[1]));
        o.z = f2bf(m * cs4.z * FEXP2(e[2]));
        o.w = f2bf(m * cs4.w * FEXP2(e[3]));
        // P[q][l]: row q = qt*16+l16, cols l-rel = (lt2&1)*16 + quad*4 .. +3
        *(ushort4*)&pt[wid][qt*16 + l16][(lt2 & 1)*16 + quad*4] = o;
      }
      // PV for the 32-l half once both sub-tiles of it are in pt
      if (lt2 & 1) {
        bf16x8 vb[4];                            // hoisted out of qt loop
        #pragma unroll
        for (int dt = 0; dt < 4; ++dt)
          vb[dt] = *(const bf16x8*)&Vt[lc & 1][dt*16 + l16]
                                      [(lt2 >> 1)*32 + quad*8];
        #pragma unroll
        for (int qt = 0; qt < 2; ++qt) {
          bf16x8 pa = *(const bf16x8*)&pt[wid][qt*16 + l16][quad*8];
          #pragma unroll
          for (int dt = 0; dt < 4; ++dt)
            acc[dt][qt] = MFMA32(pa, vb[dt], acc[dt][qt]);
        }
      }
    }
    // write NEXT chunk into the other buffer AFTER compute (T14 late write)
    if (lc < 7)
      *(ushort4*)&Vt[(lc+1) & 1][vrow][vseg] = nreg;
  }
  // ---- write out[q][d]: D row = q(quad*4+r), col = d(l16) ----
  #pragma unroll
  for (int qt = 0; qt < 2; ++qt)
    #pragma unroll
    for (int dt = 0; dt < 4; ++dt)
      #pragma unroll
      for (int r = 0; r < 4; ++r)
        oat[((size_t)(ns*LL + q0 + qt*16 + quad*4 + r))*EE + h*DD + dt*16 + l16] =
            f2bf(acc[dt][qt][r]);
}

// ---------------- K4: Y = oat @ Wo^T + bo, m97-style MFMA GEMM --------------
// 128x64 tile, BK=64 -> grid 1024 = 4 blocks/CU. 4 waves as 2x2 over
// (128m x 64n), each computing 64x32. Staging via global_load_lds width=16.
__global__ void __launch_bounds__(256) out_gemm_kernel(
    const u16* __restrict__ A, const u16* __restrict__ Wob,
    const float* __restrict__ bo, float* __restrict__ Y) {
  __shared__ u16 As[128][64];   // [m][k]  16384 B, linear for global_load_lds
  __shared__ u16 Bs[64][64];    // [n][k]   8192 B
  const int b = blockIdx.x;     // 64 mtiles x 16 ntiles
  const int nb = b & 15, mb = b >> 4;
  const int m0 = mb*128, n0 = nb*64;
  const int tid = threadIdx.x;
  const int wid = tid >> 6, lane = tid & 63, quad = lane >> 4, l16 = lane & 15;
  const int wm = (wid >> 1)*64, wn = (wid & 1)*32;   // wave sub-tile 64x32
  const int r0 = tid >> 3, sseg = (tid & 7) * 8;     // staging row/col (u16)
  u16* adst = &As[0][0] + tid*8;                     // lane-linear 16B chunks
  u16* bdst = &Bs[0][0] + tid*8;
  f32x4 z = {0.f, 0.f, 0.f, 0.f};
  f32x4 acc[4][2];
  #pragma unroll
  for (int i = 0; i < 4; ++i)
    #pragma unroll
    for (int j = 0; j < 2; ++j) acc[i][j] = z;
  for (int k0 = 0; k0 < EE; k0 += 64) {
    __syncthreads();                    // previous tile fully consumed
    #pragma unroll
    for (int it = 0; it < 4; ++it)      // A: 128 rows x 64 k
      gload16(&A[(size_t)(m0 + it*32 + r0)*EE + k0 + sseg], adst + it*2048);
    #pragma unroll
    for (int it = 0; it < 2; ++it)      // B: 64 rows x 64 k
      gload16(&Wob[(size_t)(n0 + it*32 + r0)*EE + k0 + sseg], bdst + it*2048);
    __syncthreads();                    // vmcnt(0) drain -> LDS data ready
    #pragma unroll
    for (int kk = 0; kk < 2; ++kk) {
      bf16x8 af[4], bfr[2];
      #pragma unroll
      for (int i = 0; i < 4; ++i)
        af[i] = *(const bf16x8*)&As[wm + i*16 + l16][kk*32 + quad*8];
      #pragma unroll
      for (int j = 0; j < 2; ++j)
        bfr[j] = *(const bf16x8*)&Bs[wn + j*16 + l16][kk*32 + quad*8];
      #pragma unroll
      for (int i = 0; i < 4; ++i)
        #pragma unroll
        for (int j = 0; j < 2; ++j)
          acc[i][j] = MFMA32(af[i], bfr[j], acc[i][j]);
    }
  }
  #pragma unroll
  for (int i = 0; i < 4; ++i)
    #pragma unroll
    for (int j = 0; j < 2; ++j) {
      int col = n0 + wn + j*16 + l16;
      float bias = bo[col];
      #pragma unroll
      for (int r = 0; r < 4; ++r)
        Y[(size_t)(m0 + wm + i*16 + quad*4 + r)*EE + col] = acc[i][j][r] + bias;
    }
}

extern "C" void kernel_launch(void* const* d_in, const int* in_sizes, int n_in,
                              void* d_out, int out_size, void* d_ws, size_t ws_size,
                              hipStream_t stream) {
  const float* values = (const float*)d_in[0];
  const float* keysp  = (const float*)d_in[1];
  const float* query  = (const float*)d_in[2];
  const int*   mask   = (const int*)d_in[3];
  const float* Wv = (const float*)d_in[4];
  const float* Wk = (const float*)d_in[5];
  const float* Wq = (const float*)d_in[6];
  const float* Wo = (const float*)d_in[7];
  const float* bo = (const float*)d_in[8];
  float* Y = (float*)d_out;

  u16* qp  = (u16*)d_ws;
  u16* kp  = qp + NSLE;
  u16* vpT = kp + NSLE;
  u16* oat = vpT + NSLE;
  u16* Wob = oat + NSLE;
  u16* Wvb = Wob + EE*EE;
  u16* Wkb = Wvb + DD*DD;
  u16* Wqb = Wkb + DD*DD;

  convw_kernel<<<1036, 256, 0, stream>>>(Wv, Wk, Wq, Wo, Wvb, Wkb, Wqb, Wob);
  proj_kernel<<<3*NSX*4*8, 256, 0, stream>>>(values, keysp, query,
                                             Wvb, Wkb, Wqb, vpT, kp, qp);
  attn_kernel<<<NSX*HH, 1024, 0, stream>>>(qp, kp, vpT, mask, oat);
  out_gemm_kernel<<<(NT/128)*(EE/64), 256, 0, stream>>>(oat, Wob, bo, Y);
}